// Round 12
// baseline (294.228 us; speedup 1.0000x reference)
//
#include <hip/hip_runtime.h>
#include <hip/hip_bf16.h>

typedef __attribute__((ext_vector_type(8))) __bf16 bf8_t;
typedef __attribute__((ext_vector_type(4))) float f32x4;
typedef __attribute__((ext_vector_type(16))) float f32x16;

#define GLOAD16(gptr, lptr)                                                              \
  __builtin_amdgcn_global_load_lds((const __attribute__((address_space(1))) void*)(gptr), \
                                   (__attribute__((address_space(3))) void*)(lptr), 16, 0, 0)

__device__ __forceinline__ unsigned short f2bf(float f) {
  union { float f; unsigned u; } v; v.f = f;
  return (unsigned short)((v.u + 0x7fffu + ((v.u >> 16) & 1u)) >> 16);
}

__device__ __forceinline__ float bf2f(unsigned short u) {
  union { unsigned u; float f; } v; v.u = ((unsigned)u) << 16;
  return v.f;
}

__device__ __forceinline__ unsigned cvtpk_bf16(float a, float b) {
  unsigned r;
  asm("v_cvt_pk_bf16_f32 %0, %1, %2" : "=v"(r) : "v"(a), "v"(b));
  return r;
}

// ---------- cast f32 -> bf16 ----------
__global__ void cast_bf16(const float* __restrict__ in, unsigned short* __restrict__ out, int n4) {
  int i = blockIdx.x * blockDim.x + threadIdx.x;
  if (i >= n4) return;
  float4 v = ((const float4*)in)[i];
  ushort4 o;
  o.x = f2bf(v.x); o.y = f2bf(v.y); o.z = f2bf(v.z); o.w = f2bf(v.w);
  ((ushort4*)out)[i] = o;
}

// ---------- transpose-cast ----------
__global__ void tcast(const float* __restrict__ in, unsigned short* __restrict__ out,
                      int R, int C, int ld, int rowOff) {
  __shared__ float tile[32][33];
  int c0 = blockIdx.x * 32, r0 = blockIdx.y * 32;
  int tx = threadIdx.x, ty = threadIdx.y;
#pragma unroll
  for (int i = 0; i < 4; ++i)
    tile[ty + 8 * i][tx] = in[(size_t)(r0 + ty + 8 * i) * C + c0 + tx];
  __syncthreads();
#pragma unroll
  for (int i = 0; i < 4; ++i)
    out[(size_t)(rowOff + c0 + ty + 8 * i) * ld + r0 + tx] = f2bf(tile[tx][ty + 8 * i]);
}

// ---------- 256x256-tile bf16 GEMM, BK=32, dual-barrier phase schedule ----------
// 4 LDS slots (r7 ledger, conflicts=0). Per tile: 2 phases, each
// {stage half | bar | lgkm(0)+schedbar | setprio 16-MFMA | bar | ds_read next frags}.
// Counted vmcnt BEFORE the tile-boundary barrier (barrier publishes all waves' stages).
__global__ __launch_bounds__(512, 2) void gemm256(
    const unsigned short* __restrict__ A,
    const unsigned short* __restrict__ Bt,
    float* __restrict__ C0, float* __restrict__ C1,
    unsigned short* __restrict__ Cb,
    int N, int ldk, int Kslice, int nTileN) {
  __shared__ unsigned short SM[4][2][8192];  // [slot][A|B][256 rows x 32 cols swizzled]
  int ks = blockIdx.y;
  int kbase = ks * Kslice;
  int nwg = gridDim.x;
  int bidx = blockIdx.x;
  int wg = ((bidx & 7) * (nwg >> 3)) + (bidx >> 3);  // XCD swizzle (nwg % 8 == 0)
  int bm = wg / nTileN, bn = wg % nTileN;
  int m0 = bm << 8, n0 = bn << 8;
  int tid = threadIdx.x, lane = tid & 63, w = tid >> 6;
  int wm = w >> 2, wn = w & 3;
  int lrow = lane & 15, lch = lane >> 4;
  int srow = tid >> 2;
  int scol = ((tid & 3) ^ ((srow >> 1) & 3)) << 3;
  int nt = Kslice >> 5;  // requires nt >= 3

  f32x4 acc[8][4] = {};

  auto stageA = [&](int t) {
    int buf = t & 3;
    int k0 = kbase + (t << 5);
    const unsigned short* Ag = A + (size_t)(m0 + srow) * ldk + k0 + scol;
    unsigned short* Al = &SM[buf][0][w << 9];
    GLOAD16(Ag, Al);
    GLOAD16(Ag + (size_t)128 * ldk, Al + 4096);
  };
  auto stageB = [&](int t) {
    int buf = t & 3;
    int k0 = kbase + (t << 5);
    const unsigned short* Bg = Bt + (size_t)(n0 + srow) * ldk + k0 + scol;
    unsigned short* Bl = &SM[buf][1][w << 9];
    GLOAD16(Bg, Bl);
    GLOAD16(Bg + (size_t)128 * ldk, Bl + 4096);
  };

  bf8_t bfr[4], afA[4], afB[4];
  auto readBfr = [&](int t) {
    const unsigned short* Bs = &SM[t & 3][1][0];
#pragma unroll
    for (int ni = 0; ni < 4; ++ni) {
      int br = (wn << 6) + (ni << 4) + lrow;
      bfr[ni] = *(const bf8_t*)(Bs + br * 32 + ((lch ^ ((br >> 1) & 3)) << 3));
    }
  };
  auto readAfr = [&](int t, int half, bf8_t* af) {
    const unsigned short* As = &SM[t & 3][0][0];
#pragma unroll
    for (int mi = 0; mi < 4; ++mi) {
      int ar = (wm << 7) + ((half * 4 + mi) << 4) + lrow;
      af[mi] = *(const bf8_t*)(As + ar * 32 + ((lch ^ ((ar >> 1) & 3)) << 3));
    }
  };

  // prologue: 3 tiles staged; publish tile 0; preload its fragments
  stageA(0); stageB(0); stageA(1); stageB(1); stageA(2); stageB(2);
  asm volatile("s_waitcnt vmcnt(8)" ::: "memory");
  asm volatile("s_barrier" ::: "memory");
  readBfr(0);
  readAfr(0, 0, afA);

  for (int t = 0; t < nt; ++t) {
    // ---- phase A: mi 0..3 ----
    if (t + 3 < nt) stageA(t + 3);
    asm volatile("s_barrier" ::: "memory");
    asm volatile("s_waitcnt lgkmcnt(0)" ::: "memory");
    __builtin_amdgcn_sched_barrier(0);
    __builtin_amdgcn_s_setprio(1);
#pragma unroll
    for (int mi = 0; mi < 4; ++mi)
#pragma unroll
      for (int ni = 0; ni < 4; ++ni)
        acc[mi][ni] = __builtin_amdgcn_mfma_f32_16x16x32_bf16(afA[mi], bfr[ni], acc[mi][ni], 0, 0, 0);
    __builtin_amdgcn_s_setprio(0);
    asm volatile("s_barrier" ::: "memory");
    readAfr(t, 1, afB);  // frags for phase B (slot t: safe, synced at tile entry)
    // ---- phase B: mi 4..7 ----
    if (t + 3 < nt) stageB(t + 3);
    asm volatile("s_barrier" ::: "memory");
    asm volatile("s_waitcnt lgkmcnt(0)" ::: "memory");
    __builtin_amdgcn_sched_barrier(0);
    __builtin_amdgcn_s_setprio(1);
#pragma unroll
    for (int mi = 0; mi < 4; ++mi)
#pragma unroll
      for (int ni = 0; ni < 4; ++ni)
        acc[4 + mi][ni] = __builtin_amdgcn_mfma_f32_16x16x32_bf16(afB[mi], bfr[ni], acc[4 + mi][ni], 0, 0, 0);
    __builtin_amdgcn_s_setprio(0);
    if (t + 1 < nt) {
      // guarantee tile t+1 landed for ALL waves: own vmcnt, then barrier publishes
      if (t + 3 < nt)      asm volatile("s_waitcnt vmcnt(8)" ::: "memory");
      else if (t + 2 < nt) asm volatile("s_waitcnt vmcnt(4)" ::: "memory");
      else                 asm volatile("s_waitcnt vmcnt(0)" ::: "memory");
      asm volatile("s_barrier" ::: "memory");
      readBfr(t + 1);
      readAfr(t + 1, 0, afA);
    } else {
      asm volatile("s_barrier" ::: "memory");
    }
  }

  int r0 = m0 + (wm << 7) + (lch << 2);
  int c0 = n0 + (wn << 6) + lrow;
  if (Cb) {
#pragma unroll
    for (int mi = 0; mi < 8; ++mi)
#pragma unroll
      for (int ni = 0; ni < 4; ++ni)
#pragma unroll
        for (int r = 0; r < 4; ++r)
          Cb[(size_t)(r0 + (mi << 4) + r) * N + c0 + (ni << 4)] = f2bf(acc[mi][ni][r]);
  } else {
    float* __restrict__ C = ks ? C1 : C0;
#pragma unroll
    for (int mi = 0; mi < 8; ++mi)
#pragma unroll
      for (int ni = 0; ni < 4; ++ni)
#pragma unroll
        for (int r = 0; r < 4; ++r)
          C[(size_t)(r0 + (mi << 4) + r) * N + c0 + (ni << 4)] = acc[mi][ni][r];
  }
}

// ---------- split-K reduce ----------
__global__ void reduce_add(const float4* __restrict__ a, const float4* __restrict__ b,
                           float4* __restrict__ o, int n4) {
  int i = blockIdx.x * blockDim.x + threadIdx.x;
  if (i >= n4) return;
  float4 x = a[i], y = b[i];
  o[i] = make_float4(x.x + y.x, x.y + y.y, x.z + y.z, x.w + y.w);
}

// ---------- fused RMS-norm + RoPE + layout shuffle (bf16 input) ----------
// K rows are pre-scaled by scale*log2(e) so attn's exp2 needs no multiply.
__global__ __launch_bounds__(128) void normrope(
    const unsigned short* __restrict__ qkv, const int* __restrict__ positions,
    const float* __restrict__ qw, const float* __restrict__ kw,
    unsigned short* __restrict__ qb, unsigned short* __restrict__ kb,
    unsigned short* __restrict__ vt) {
  int blk = blockIdx.x;
  int hh = blk % 48, bt = blk / 48;
  int b = bt >> 10, t = bt & 1023;
  int tid = threadIdx.x;
  int colbase = (hh < 32) ? (hh << 7) : ((hh < 40) ? (4096 + ((hh - 32) << 7)) : (5120 + ((hh - 40) << 7)));
  float val = bf2f(qkv[(size_t)bt * 6144 + colbase + tid]);
  if (hh >= 40) {
    vt[((size_t)((b * 8 + hh - 40) * 128 + tid)) * 1024 + t] = f2bf(val);
    return;
  }
  __shared__ float red[2];
  __shared__ float xs[128];
  float ss = val * val;
#pragma unroll
  for (int m = 32; m >= 1; m >>= 1) ss += __shfl_xor(ss, m);
  if ((tid & 63) == 0) red[tid >> 6] = ss;
  __syncthreads();
  float rinv = rsqrtf((red[0] + red[1]) * (1.0f / 128.0f) + 1e-6f);
  float wgt = (hh < 32) ? qw[tid] : kw[tid];
  float xn = val * rinv * wgt;
  xs[tid] = xn;
  __syncthreads();
  float other = xs[tid ^ 64];
  int pos = positions[b * 1024 + t];
  int j = tid & 63;
  float ang = (float)pos * exp2f(-(float)j * 0.31143075889569027f);
  float sv = sinf(ang), cv = cosf(ang);
  float outv = (tid < 64) ? (xn * cv - other * sv) : (xn * cv + other * sv);
  if (hh >= 32) outv *= 0.12751744f;  // fold (1/sqrt(128))*log2(e) into K
  unsigned short o = f2bf(outv);
  if (hh < 32) qb[((size_t)((b * 32 + hh) * 1024 + t)) * 128 + tid] = o;
  else kb[((size_t)((b * 8 + hh - 32) * 1024 + t)) * 128 + tid] = o;
}

// ---------- flash attention v4: swapped 32x32 MFMA, in-reg softmax, defer-max, setprio ----------
__global__ __launch_bounds__(256, 2) void attn(
    const unsigned short* __restrict__ qb,
    const unsigned short* __restrict__ kb,
    const unsigned short* __restrict__ vt,
    unsigned short* __restrict__ ob) {
  __shared__ unsigned short Kl[2][64 * 128];   // 16B-slot swizzle: slot ^ (row&15)
  __shared__ unsigned short Vl[2][128 * 64];   // V^T tile; slot ^ (row&7)
  int bx = blockIdx.x, hq = blockIdx.y, b = blockIdx.z;
  int qt = (bx < 4) ? (7 - bx) : (bx - 4);     // longest-first dispatch (LPT)
  int kvh = hq >> 2;
  int tid = threadIdx.x, lane = tid & 63, w = tid >> 6;
  int qlane = lane & 31, h = lane >> 5;
  int q0 = (qt << 7) + (w << 5);
  int qg = q0 + qlane;
  const unsigned short* kbase = kb + ((size_t)(b * 8 + kvh) << 17);
  const unsigned short* vbase = vt + ((size_t)(b * 8 + kvh) << 17);

  const unsigned short* qptr = qb + ((size_t)((b * 32 + hq) * 1024 + qg) << 7) + (h << 3);
  bf8_t qf[8];
#pragma unroll
  for (int ds = 0; ds < 8; ++ds) qf[ds] = *(const bf8_t*)(qptr + ds * 16);

  f32x16 o[4] = {};
  float mrun = -3.0e38f, lrun = 0.f;
  int last_st = (q0 + 31) >> 6;
  int nsteps = 2 * qt + 2;

  auto stage = [&](int st, int buf) {
    int s0 = st << 6;
    unsigned short* kd = &Kl[buf][0];
    unsigned short* vd = &Vl[buf][0];
#pragma unroll
    for (int i = 0; i < 4; ++i) {
      int cid = i * 256 + tid;
      int kr = cid >> 4, ksl = cid & 15;
      GLOAD16(kbase + (size_t)(s0 + kr) * 128 + ((ksl ^ (kr & 15)) << 3), kd + cid * 8);
      int vr = cid >> 3, vsl = cid & 7;
      GLOAD16(vbase + (size_t)vr * 1024 + s0 + ((vsl ^ (vr & 7)) << 3), vd + cid * 8);
    }
  };

  stage(0, 0);
  for (int st = 0; st < nsteps; ++st) {
    __syncthreads();
    if (st + 1 < nsteps) stage(st + 1, (st + 1) & 1);
    if (st <= last_st) {
      const char* Kb = (const char*)&Kl[st & 1][0];
      const char* Vb = (const char*)&Vl[st & 1][0];
      // ---- QK^T (swapped): S[k][q], K pre-scaled by scale*log2e ----
      f32x16 s0v = {}, s1v = {};
      __builtin_amdgcn_s_setprio(1);
#pragma unroll
      for (int ds = 0; ds < 8; ++ds) {
        int c = ds * 2 + h;
        int r0 = qlane, r1 = 32 + qlane;
        bf8_t k0 = *(const bf8_t*)(Kb + r0 * 256 + ((c ^ (r0 & 15)) << 4));
        bf8_t k1 = *(const bf8_t*)(Kb + r1 * 256 + ((c ^ (r1 & 15)) << 4));
        s0v = __builtin_amdgcn_mfma_f32_32x32x16_bf16(k0, qf[ds], s0v, 0, 0, 0);
        s1v = __builtin_amdgcn_mfma_f32_32x32x16_bf16(k1, qf[ds], s1v, 0, 0, 0);
      }
      __builtin_amdgcn_s_setprio(0);
      // ---- mask + row-max ----
      bool dm = (st == last_st);
      int kg0 = st << 6;
      float mt = -3.0e38f;
#pragma unroll
      for (int e = 0; e < 16; ++e) {
        int kl = (e & 3) + 8 * (e >> 2) + 4 * h;
        if (dm) {
          if (kg0 + kl > qg) s0v[e] = -3.0e38f;
          if (kg0 + 32 + kl > qg) s1v[e] = -3.0e38f;
        }
        mt = fmaxf(mt, fmaxf(s0v[e], s1v[e]));
      }
      mt = fmaxf(mt, __shfl_xor(mt, 32));
      // ---- defer-max (T13): rescale only when max grew past THR=8 ----
      if (!__all(mt - mrun <= 8.0f)) {
        float mnew = fmaxf(mrun, mt);
        float alpha = exp2f(mrun - mnew);
        lrun *= alpha;
#pragma unroll
        for (int db = 0; db < 4; ++db)
#pragma unroll
          for (int e = 0; e < 16; ++e) o[db][e] *= alpha;
        mrun = mnew;
      }
      // ---- exp + row-sum (no scale mul: K pre-scaled) ----
      float ls = 0.f;
#pragma unroll
      for (int e = 0; e < 16; ++e) {
        s0v[e] = exp2f(s0v[e] - mrun);
        s1v[e] = exp2f(s1v[e] - mrun);
        ls += s0v[e] + s1v[e];
      }
      ls += __shfl_xor(ls, 32);
      lrun += ls;
      // ---- P repack to B-frags in-register (cvt_pk + lane^32 exchange) ----
      bf8_t pf[4];
#pragma unroll
      for (int s = 0; s < 4; ++s) {
        unsigned w00, w01, w10, w11;
        {
          const int B0 = 4 * ((2 * s) & 3);
          if ((2 * s) >> 2) { w00 = cvtpk_bf16(s1v[B0], s1v[B0 + 1]); w01 = cvtpk_bf16(s1v[B0 + 2], s1v[B0 + 3]); }
          else              { w00 = cvtpk_bf16(s0v[B0], s0v[B0 + 1]); w01 = cvtpk_bf16(s0v[B0 + 2], s0v[B0 + 3]); }
        }
        {
          const int B1 = 4 * ((2 * s + 1) & 3);
          if ((2 * s + 1) >> 2) { w10 = cvtpk_bf16(s1v[B1], s1v[B1 + 1]); w11 = cvtpk_bf16(s1v[B1 + 2], s1v[B1 + 3]); }
          else                  { w10 = cvtpk_bf16(s0v[B1], s0v[B1 + 1]); w11 = cvtpk_bf16(s0v[B1 + 2], s0v[B1 + 3]); }
        }
        unsigned sa = h ? w00 : w10, sb = h ? w01 : w11;
        unsigned ra = __shfl_xor(sa, 32), rb = __shfl_xor(sb, 32);
        unsigned ka = h ? w10 : w00, kb2 = h ? w11 : w01;
        unsigned f0 = h ? ra : ka, f1 = h ? rb : kb2;
        unsigned f2 = h ? ka : ra, f3 = h ? kb2 : rb;
        uint4 fv = make_uint4(f0, f1, f2, f3);
        pf[s] = *(bf8_t*)&fv;
      }
      // ---- PV (swapped): O[d][q] += V^T-frag x P-frag ----
      __builtin_amdgcn_s_setprio(1);
#pragma unroll
      for (int db = 0; db < 4; ++db) {
        int vr = (db << 5) + qlane;
#pragma unroll
        for (int s = 0; s < 4; ++s) {
          int c = (s << 1) + h;
          bf8_t vf = *(const bf8_t*)(Vb + vr * 128 + ((c ^ (vr & 7)) << 4));
          o[db] = __builtin_amdgcn_mfma_f32_32x32x16_bf16(vf, pf[s], o[db], 0, 0, 0);
        }
      }
      __builtin_amdgcn_s_setprio(0);
    }
  }

  __syncthreads();
  unsigned short* tb = &Kl[0][0] + (w << 12);
  float inv = 1.0f / lrun;
#pragma unroll
  for (int db = 0; db < 4; ++db)
#pragma unroll
    for (int rq = 0; rq < 4; ++rq) {
      int d0 = (db << 5) + (rq << 3) + (h << 2);
      unsigned lo = ((unsigned)f2bf(o[db][rq * 4 + 1] * inv) << 16) | f2bf(o[db][rq * 4 + 0] * inv);
      unsigned hi = ((unsigned)f2bf(o[db][rq * 4 + 3] * inv) << 16) | f2bf(o[db][rq * 4 + 2] * inv);
      *(uint2*)(tb + qlane * 128 + (d0 ^ ((qlane & 15) << 3))) = make_uint2(lo, hi);
    }
  int rr = lane >> 1, dh = (lane & 1) << 6;
  size_t orow = ((size_t)(b * 1024 + q0 + rr) << 12) + (hq << 7);
#pragma unroll
  for (int i = 0; i < 8; ++i) {
    int d8 = dh + i * 8;
    uint4 vv = *(const uint4*)(tb + rr * 128 + (d8 ^ ((rr & 15) << 3)));
    *(uint4*)(&ob[orow + d8]) = vv;
  }
}

extern "C" void kernel_launch(void* const* d_in, const int* in_sizes, int n_in,
                              void* d_out, int out_size, void* d_ws, size_t ws_size,
                              hipStream_t stream) {
  const float* x = (const float*)d_in[0];
  const int* positions = (const int*)d_in[1];
  const float* wq = (const float*)d_in[3];
  const float* wk = (const float*)d_in[4];
  const float* wv = (const float*)d_in[5];
  const float* wo = (const float*)d_in[6];
  const float* qnw = (const float*)d_in[7];
  const float* knw = (const float*)d_in[8];
  float* out = (float*)d_out;

  char* ws = (char*)d_ws;
  unsigned short* x_bf  = (unsigned short*)(ws);              // 2048x2560 bf16
  unsigned short* wqkvT = (unsigned short*)(ws + 10485760);   // 6144x2560 bf16
  unsigned short* woT   = (unsigned short*)(ws + 41943040);   // 2560x4096 bf16
  unsigned short* qkvb  = (unsigned short*)(ws + 62914560);   // 2048x6144 bf16 (dead after normrope)
  float*          p0    = (float*)(ws + 62914560);            // split-K partial 0 (reuses qkvb)
  float*          p1    = (float*)(ws + 83886080);            // split-K partial 1
  unsigned short* q_bf  = (unsigned short*)(ws + 113246208);  // [2][32][1024][128]
  unsigned short* k_bf  = (unsigned short*)(ws + 130023424);  // [2][8][1024][128]
  unsigned short* vt_bf = (unsigned short*)(ws + 134217728);  // [2][8][128][1024]
  unsigned short* a_bf  = (unsigned short*)(ws + 138412032);  // 2048x4096 bf16

  cast_bf16<<<5120, 256, 0, stream>>>(x, x_bf, 2048 * 2560 / 4);
  tcast<<<dim3(128, 80), dim3(32, 8), 0, stream>>>(wq, wqkvT, 2560, 4096, 2560, 0);
  tcast<<<dim3(32, 80), dim3(32, 8), 0, stream>>>(wk, wqkvT, 2560, 1024, 2560, 4096);
  tcast<<<dim3(32, 80), dim3(32, 8), 0, stream>>>(wv, wqkvT, 2560, 1024, 2560, 5120);
  tcast<<<dim3(80, 128), dim3(32, 8), 0, stream>>>(wo, woT, 4096, 2560, 4096, 0);
  // QKV projection: 2048x6144x2560, bf16 output
  gemm256<<<dim3(8 * 24, 1), 512, 0, stream>>>(x_bf, wqkvT, nullptr, nullptr, qkvb,
                                               6144, 2560, 2560, 24);
  normrope<<<2048 * 48, 128, 0, stream>>>(qkvb, positions, qnw, knw, q_bf, k_bf, vt_bf);
  attn<<<dim3(8, 32, 2), 256, 0, stream>>>(q_bf, k_bf, vt_bf, a_bf);
  // out-projection: 2048x2560x4096, split-K=2, f32 partials
  gemm256<<<dim3(8 * 10, 2), 512, 0, stream>>>(a_bf, woT, p0, p1, nullptr, 2560, 4096, 2048, 10);
  reduce_add<<<5120, 256, 0, stream>>>((const float4*)p0, (const float4*)p1, (float4*)out,
                                       2048 * 2560 / 4);
}

// Round 13
// 288.861 us; speedup vs baseline: 1.0186x; 1.0186x over previous
//
#include <hip/hip_runtime.h>
#include <hip/hip_bf16.h>

typedef __attribute__((ext_vector_type(8))) __bf16 bf8_t;
typedef __attribute__((ext_vector_type(4))) float f32x4;
typedef __attribute__((ext_vector_type(16))) float f32x16;

#define GLOAD16(gptr, lptr)                                                              \
  __builtin_amdgcn_global_load_lds((const __attribute__((address_space(1))) void*)(gptr), \
                                   (__attribute__((address_space(3))) void*)(lptr), 16, 0, 0)

__device__ __forceinline__ unsigned short f2bf(float f) {
  union { float f; unsigned u; } v; v.f = f;
  return (unsigned short)((v.u + 0x7fffu + ((v.u >> 16) & 1u)) >> 16);
}

__device__ __forceinline__ float bf2f(unsigned short u) {
  union { unsigned u; float f; } v; v.u = ((unsigned)u) << 16;
  return v.f;
}

__device__ __forceinline__ unsigned cvtpk_bf16(float a, float b) {
  unsigned r;
  asm("v_cvt_pk_bf16_f32 %0, %1, %2" : "=v"(r) : "v"(a), "v"(b));
  return r;
}

// ---------- cast f32 -> bf16 ----------
__global__ void cast_bf16(const float* __restrict__ in, unsigned short* __restrict__ out, int n4) {
  int i = blockIdx.x * blockDim.x + threadIdx.x;
  if (i >= n4) return;
  float4 v = ((const float4*)in)[i];
  ushort4 o;
  o.x = f2bf(v.x); o.y = f2bf(v.y); o.z = f2bf(v.z); o.w = f2bf(v.w);
  ((ushort4*)out)[i] = o;
}

// ---------- vectorized transpose-cast: in[R][C] f32 -> out[(rowOff+c)*ld + r] bf16 ----------
// Tile 32 rows x 128 cols; float4 reads, uint4 (8xbf16) writes. LDS stride 40 (16B-aligned).
__global__ __launch_bounds__(256) void tcast4(const float* __restrict__ in,
                                              unsigned short* __restrict__ out,
                                              int C, int ld, int rowOff) {
  __shared__ float tile[128][40];
  int c0 = blockIdx.x * 128, r0 = blockIdx.y * 32;
  int tid = threadIdx.x;
  int tx = tid & 31, ty = tid >> 5;
  float4 v[4];
#pragma unroll
  for (int i = 0; i < 4; ++i)
    v[i] = *(const float4*)(in + (size_t)(r0 + (ty << 2) + i) * C + c0 + (tx << 2));
#pragma unroll
  for (int j = 0; j < 4; ++j) {
    float4 t4 = make_float4(v[0].x, v[1].x, v[2].x, v[3].x);
    if (j == 1) t4 = make_float4(v[0].y, v[1].y, v[2].y, v[3].y);
    if (j == 2) t4 = make_float4(v[0].z, v[1].z, v[2].z, v[3].z);
    if (j == 3) t4 = make_float4(v[0].w, v[1].w, v[2].w, v[3].w);
    *(float4*)(&tile[(tx << 2) + j][ty << 2]) = t4;
  }
  __syncthreads();
  int p = tid & 3;
#pragma unroll
  for (int half = 0; half < 2; ++half) {
    int cc = (tid >> 2) + half * 64;
    const float* row = &tile[cc][p << 3];
    unsigned u0 = ((unsigned)f2bf(row[1]) << 16) | f2bf(row[0]);
    unsigned u1 = ((unsigned)f2bf(row[3]) << 16) | f2bf(row[2]);
    unsigned u2 = ((unsigned)f2bf(row[5]) << 16) | f2bf(row[4]);
    unsigned u3 = ((unsigned)f2bf(row[7]) << 16) | f2bf(row[6]);
    *(uint4*)(out + (size_t)(rowOff + c0 + cc) * ld + r0 + (p << 3)) = make_uint4(u0, u1, u2, u3);
  }
}

// ---------- 256x256-tile bf16 GEMM, BK=32, 4-buffer 3-deep counted-vmcnt pipeline ----------
// (r7 winner, frozen pipeline) Swizzle ch' = ch ^ ((row>>1)&3) both sides; conflicts = 0.
// f32 out to Cf + ks*pstride (split-K), or bf16 to Cb. Slice ks: Ks0 (last slice padded to Ktot).
__global__ __launch_bounds__(512, 2) void gemm256(
    const unsigned short* __restrict__ A,
    const unsigned short* __restrict__ Bt,
    float* __restrict__ Cf, unsigned short* __restrict__ Cb,
    int N, int ldk, int Ks0, int Ktot, int nTileN, long long pstride) {
  __shared__ unsigned short SM[4][2][8192];
  int ks = blockIdx.y;
  int kbase = ks * Ks0;
  int Kslice = (ks == (int)gridDim.y - 1) ? (Ktot - kbase) : Ks0;
  int nwg = gridDim.x;
  int bidx = blockIdx.x;
  int wg = ((bidx & 7) * (nwg >> 3)) + (bidx >> 3);  // XCD swizzle (nwg % 8 == 0)
  int bm = wg / nTileN, bn = wg % nTileN;
  int m0 = bm << 8, n0 = bn << 8;
  int tid = threadIdx.x, lane = tid & 63, w = tid >> 6;
  int wm = w >> 2, wn = w & 3;
  int lrow = lane & 15, lch = lane >> 4;
  int srow = tid >> 2;
  int scol = ((tid & 3) ^ ((srow >> 1) & 3)) << 3;
  int nt = Kslice >> 5;

  f32x4 acc[8][4] = {};

  auto stage = [&](int t) {
    int buf = t & 3;
    int k0 = kbase + (t << 5);
    const unsigned short* Ag = A + (size_t)(m0 + srow) * ldk + k0 + scol;
    const unsigned short* Bg = Bt + (size_t)(n0 + srow) * ldk + k0 + scol;
    unsigned short* Al = &SM[buf][0][w << 9];
    unsigned short* Bl = &SM[buf][1][w << 9];
    GLOAD16(Ag, Al);
    GLOAD16(Ag + (size_t)128 * ldk, Al + 4096);
    GLOAD16(Bg, Bl);
    GLOAD16(Bg + (size_t)128 * ldk, Bl + 4096);
  };

  stage(0);
  stage(1);
  stage(2);
  for (int t = 0; t < nt; ++t) {
    if (t + 2 < nt)      asm volatile("s_waitcnt vmcnt(8)" ::: "memory");
    else if (t + 1 < nt) asm volatile("s_waitcnt vmcnt(4)" ::: "memory");
    else                 asm volatile("s_waitcnt vmcnt(0)" ::: "memory");
    asm volatile("s_barrier" ::: "memory");
    if (t + 3 < nt) stage(t + 3);
    int buf = t & 3;
    const unsigned short* As = &SM[buf][0][0];
    const unsigned short* Bs = &SM[buf][1][0];
    bf8_t a[8], b[4];
#pragma unroll
    for (int mi = 0; mi < 8; ++mi) {
      int ar = (wm << 7) + (mi << 4) + lrow;
      a[mi] = *(const bf8_t*)(As + ar * 32 + ((lch ^ ((ar >> 1) & 3)) << 3));
    }
#pragma unroll
    for (int ni = 0; ni < 4; ++ni) {
      int br = (wn << 6) + (ni << 4) + lrow;
      b[ni] = *(const bf8_t*)(Bs + br * 32 + ((lch ^ ((br >> 1) & 3)) << 3));
    }
    __builtin_amdgcn_s_setprio(1);
#pragma unroll
    for (int mi = 0; mi < 8; ++mi)
#pragma unroll
      for (int ni = 0; ni < 4; ++ni)
        acc[mi][ni] = __builtin_amdgcn_mfma_f32_16x16x32_bf16(a[mi], b[ni], acc[mi][ni], 0, 0, 0);
    __builtin_amdgcn_s_setprio(0);
  }
  int r0 = m0 + (wm << 7) + (lch << 2);
  int c0 = n0 + (wn << 6) + lrow;
  if (Cb) {
#pragma unroll
    for (int mi = 0; mi < 8; ++mi)
#pragma unroll
      for (int ni = 0; ni < 4; ++ni)
#pragma unroll
        for (int r = 0; r < 4; ++r)
          Cb[(size_t)(r0 + (mi << 4) + r) * N + c0 + (ni << 4)] = f2bf(acc[mi][ni][r]);
  } else {
    float* __restrict__ C = Cf + (size_t)ks * pstride;
#pragma unroll
    for (int mi = 0; mi < 8; ++mi)
#pragma unroll
      for (int ni = 0; ni < 4; ++ni)
#pragma unroll
        for (int r = 0; r < 4; ++r)
          C[(size_t)(r0 + (mi << 4) + r) * N + c0 + (ni << 4)] = acc[mi][ni][r];
  }
}

// ---------- split-K 3-way reduce ----------
__global__ void reduce3(const float4* __restrict__ a, const float4* __restrict__ b,
                        const float4* __restrict__ c, float4* __restrict__ o, int n4) {
  int i = blockIdx.x * blockDim.x + threadIdx.x;
  if (i >= n4) return;
  float4 x = a[i], y = b[i], z = c[i];
  o[i] = make_float4(x.x + y.x + z.x, x.y + y.y + z.y, x.z + y.z + z.z, x.w + y.w + z.w);
}

// ---------- fused RMS-norm + RoPE + layout shuffle (bf16 input) ----------
// K rows are pre-scaled by scale*log2(e) so attn's exp2 needs no multiply.
__global__ __launch_bounds__(128) void normrope(
    const unsigned short* __restrict__ qkv, const int* __restrict__ positions,
    const float* __restrict__ qw, const float* __restrict__ kw,
    unsigned short* __restrict__ qb, unsigned short* __restrict__ kb,
    unsigned short* __restrict__ vt) {
  int blk = blockIdx.x;
  int hh = blk % 48, bt = blk / 48;
  int b = bt >> 10, t = bt & 1023;
  int tid = threadIdx.x;
  int colbase = (hh < 32) ? (hh << 7) : ((hh < 40) ? (4096 + ((hh - 32) << 7)) : (5120 + ((hh - 40) << 7)));
  float val = bf2f(qkv[(size_t)bt * 6144 + colbase + tid]);
  if (hh >= 40) {
    vt[((size_t)((b * 8 + hh - 40) * 128 + tid)) * 1024 + t] = f2bf(val);
    return;
  }
  __shared__ float red[2];
  __shared__ float xs[128];
  float ss = val * val;
#pragma unroll
  for (int m = 32; m >= 1; m >>= 1) ss += __shfl_xor(ss, m);
  if ((tid & 63) == 0) red[tid >> 6] = ss;
  __syncthreads();
  float rinv = rsqrtf((red[0] + red[1]) * (1.0f / 128.0f) + 1e-6f);
  float wgt = (hh < 32) ? qw[tid] : kw[tid];
  float xn = val * rinv * wgt;
  xs[tid] = xn;
  __syncthreads();
  float other = xs[tid ^ 64];
  int pos = positions[b * 1024 + t];
  int j = tid & 63;
  float ang = (float)pos * exp2f(-(float)j * 0.31143075889569027f);
  float sv = sinf(ang), cv = cosf(ang);
  float outv = (tid < 64) ? (xn * cv - other * sv) : (xn * cv + other * sv);
  if (hh >= 32) outv *= 0.12751744f;  // fold (1/sqrt(128))*log2(e) into K
  unsigned short o = f2bf(outv);
  if (hh < 32) qb[((size_t)((b * 32 + hh) * 1024 + t)) * 128 + tid] = o;
  else kb[((size_t)((b * 8 + hh - 32) * 1024 + t)) * 128 + tid] = o;
}

// ---------- flash attention v5: K in LDS, V^T direct from global (L2-resident, m169) ----------
__global__ __launch_bounds__(256, 2) void attn(
    const unsigned short* __restrict__ qb,
    const unsigned short* __restrict__ kb,
    const unsigned short* __restrict__ vt,
    unsigned short* __restrict__ ob) {
  __shared__ unsigned short Kl[2][64 * 128];   // 16B-slot swizzle: slot ^ (row&15)
  int bx = blockIdx.x, hq = blockIdx.y, b = blockIdx.z;
  int qt = (bx < 4) ? (7 - bx) : (bx - 4);     // longest-first dispatch (LPT)
  int kvh = hq >> 2;
  int tid = threadIdx.x, lane = tid & 63, w = tid >> 6;
  int qlane = lane & 31, h = lane >> 5;
  int q0 = (qt << 7) + (w << 5);
  int qg = q0 + qlane;
  const unsigned short* kbase = kb + ((size_t)(b * 8 + kvh) << 17);
  const unsigned short* vbase = vt + ((size_t)(b * 8 + kvh) << 17);

  const unsigned short* qptr = qb + ((size_t)((b * 32 + hq) * 1024 + qg) << 7) + (h << 3);
  bf8_t qf[8];
#pragma unroll
  for (int ds = 0; ds < 8; ++ds) qf[ds] = *(const bf8_t*)(qptr + ds * 16);

  f32x16 o[4] = {};
  float mrun = -3.0e38f, lrun = 0.f;
  int last_st = (q0 + 31) >> 6;
  int nsteps = 2 * qt + 2;

  auto stage = [&](int st, int buf) {
    int s0 = st << 6;
    unsigned short* kd = &Kl[buf][0];
#pragma unroll
    for (int i = 0; i < 4; ++i) {
      int cid = i * 256 + tid;
      int kr = cid >> 4, ksl = cid & 15;
      GLOAD16(kbase + (size_t)(s0 + kr) * 128 + ((ksl ^ (kr & 15)) << 3), kd + cid * 8);
    }
  };

  stage(0, 0);
  for (int st = 0; st < nsteps; ++st) {
    __syncthreads();
    if (st + 1 < nsteps) stage(st + 1, (st + 1) & 1);
    if (st <= last_st) {
      const char* Kb = (const char*)&Kl[st & 1][0];
      int s0 = st << 6;
      // ---- QK^T (swapped): S[k][q], K pre-scaled by scale*log2e ----
      f32x16 s0v = {}, s1v = {};
      __builtin_amdgcn_s_setprio(1);
#pragma unroll
      for (int ds = 0; ds < 8; ++ds) {
        int c = ds * 2 + h;
        int r0 = qlane, r1 = 32 + qlane;
        bf8_t k0 = *(const bf8_t*)(Kb + r0 * 256 + ((c ^ (r0 & 15)) << 4));
        bf8_t k1 = *(const bf8_t*)(Kb + r1 * 256 + ((c ^ (r1 & 15)) << 4));
        s0v = __builtin_amdgcn_mfma_f32_32x32x16_bf16(k0, qf[ds], s0v, 0, 0, 0);
        s1v = __builtin_amdgcn_mfma_f32_32x32x16_bf16(k1, qf[ds], s1v, 0, 0, 0);
      }
      __builtin_amdgcn_s_setprio(0);
      // ---- V^T fragments from global (L2/L1-resident; hoisted above softmax) ----
      bf8_t vf[4][4];
#pragma unroll
      for (int db = 0; db < 4; ++db) {
        const unsigned short* vr = vbase + (size_t)((db << 5) + qlane) * 1024 + s0;
#pragma unroll
        for (int s = 0; s < 4; ++s)
          vf[db][s] = *(const bf8_t*)(vr + ((s << 1) + h) * 8);
      }
      // ---- mask + row-max ----
      bool dm = (st == last_st);
      float mt = -3.0e38f;
#pragma unroll
      for (int e = 0; e < 16; ++e) {
        int kl = (e & 3) + 8 * (e >> 2) + 4 * h;
        if (dm) {
          if (s0 + kl > qg) s0v[e] = -3.0e38f;
          if (s0 + 32 + kl > qg) s1v[e] = -3.0e38f;
        }
        mt = fmaxf(mt, fmaxf(s0v[e], s1v[e]));
      }
      mt = fmaxf(mt, __shfl_xor(mt, 32));
      // ---- defer-max (T13): rescale only when max grew past THR=8 ----
      if (!__all(mt - mrun <= 8.0f)) {
        float mnew = fmaxf(mrun, mt);
        float alpha = exp2f(mrun - mnew);
        lrun *= alpha;
#pragma unroll
        for (int db = 0; db < 4; ++db)
#pragma unroll
          for (int e = 0; e < 16; ++e) o[db][e] *= alpha;
        mrun = mnew;
      }
      // ---- exp + row-sum ----
      float ls = 0.f;
#pragma unroll
      for (int e = 0; e < 16; ++e) {
        s0v[e] = exp2f(s0v[e] - mrun);
        s1v[e] = exp2f(s1v[e] - mrun);
        ls += s0v[e] + s1v[e];
      }
      ls += __shfl_xor(ls, 32);
      lrun += ls;
      // ---- P repack to B-frags in-register (cvt_pk + lane^32 exchange) ----
      bf8_t pf[4];
#pragma unroll
      for (int s = 0; s < 4; ++s) {
        unsigned w00, w01, w10, w11;
        {
          const int B0 = 4 * ((2 * s) & 3);
          if ((2 * s) >> 2) { w00 = cvtpk_bf16(s1v[B0], s1v[B0 + 1]); w01 = cvtpk_bf16(s1v[B0 + 2], s1v[B0 + 3]); }
          else              { w00 = cvtpk_bf16(s0v[B0], s0v[B0 + 1]); w01 = cvtpk_bf16(s0v[B0 + 2], s0v[B0 + 3]); }
        }
        {
          const int B1 = 4 * ((2 * s + 1) & 3);
          if ((2 * s + 1) >> 2) { w10 = cvtpk_bf16(s1v[B1], s1v[B1 + 1]); w11 = cvtpk_bf16(s1v[B1 + 2], s1v[B1 + 3]); }
          else                  { w10 = cvtpk_bf16(s0v[B1], s0v[B1 + 1]); w11 = cvtpk_bf16(s0v[B1 + 2], s0v[B1 + 3]); }
        }
        unsigned sa = h ? w00 : w10, sb = h ? w01 : w11;
        unsigned ra = __shfl_xor(sa, 32), rb = __shfl_xor(sb, 32);
        unsigned ka = h ? w10 : w00, kb2 = h ? w11 : w01;
        unsigned f0 = h ? ra : ka, f1 = h ? rb : kb2;
        unsigned f2 = h ? ka : ra, f3 = h ? kb2 : rb;
        uint4 fv = make_uint4(f0, f1, f2, f3);
        pf[s] = *(bf8_t*)&fv;
      }
      // ---- PV (swapped): O[d][q] += V^T-frag x P-frag ----
      __builtin_amdgcn_s_setprio(1);
#pragma unroll
      for (int db = 0; db < 4; ++db)
#pragma unroll
        for (int s = 0; s < 4; ++s)
          o[db] = __builtin_amdgcn_mfma_f32_32x32x16_bf16(vf[db][s], pf[s], o[db], 0, 0, 0);
      __builtin_amdgcn_s_setprio(0);
    }
  }

  __syncthreads();
  unsigned short* tb = &Kl[0][0] + (w << 12);
  float inv = 1.0f / lrun;
#pragma unroll
  for (int db = 0; db < 4; ++db)
#pragma unroll
    for (int rq = 0; rq < 4; ++rq) {
      int d0 = (db << 5) + (rq << 3) + (h << 2);
      unsigned lo = ((unsigned)f2bf(o[db][rq * 4 + 1] * inv) << 16) | f2bf(o[db][rq * 4 + 0] * inv);
      unsigned hi = ((unsigned)f2bf(o[db][rq * 4 + 3] * inv) << 16) | f2bf(o[db][rq * 4 + 2] * inv);
      *(uint2*)(tb + qlane * 128 + (d0 ^ ((qlane & 15) << 3))) = make_uint2(lo, hi);
    }
  int rr = lane >> 1, dh = (lane & 1) << 6;
  size_t orow = ((size_t)(b * 1024 + q0 + rr) << 12) + (hq << 7);
#pragma unroll
  for (int i = 0; i < 8; ++i) {
    int d8 = dh + i * 8;
    uint4 vv = *(const uint4*)(tb + rr * 128 + (d8 ^ ((rr & 15) << 3)));
    *(uint4*)(&ob[orow + d8]) = vv;
  }
}

extern "C" void kernel_launch(void* const* d_in, const int* in_sizes, int n_in,
                              void* d_out, int out_size, void* d_ws, size_t ws_size,
                              hipStream_t stream) {
  const float* x = (const float*)d_in[0];
  const int* positions = (const int*)d_in[1];
  const float* wq = (const float*)d_in[3];
  const float* wk = (const float*)d_in[4];
  const float* wv = (const float*)d_in[5];
  const float* wo = (const float*)d_in[6];
  const float* qnw = (const float*)d_in[7];
  const float* knw = (const float*)d_in[8];
  float* out = (float*)d_out;

  char* ws = (char*)d_ws;
  unsigned short* x_bf  = (unsigned short*)(ws);              // 2048x2560 bf16
  unsigned short* wqkvT = (unsigned short*)(ws + 10485760);   // 6144x2560 bf16
  unsigned short* woT   = (unsigned short*)(ws + 41943040);   // 2560x4096 bf16
  unsigned short* qkvb  = (unsigned short*)(ws + 62914560);   // 2048x6144 bf16 (dead after normrope)
  float*          p0    = (float*)(ws + 62914560);            // split-K partials x3 (reuse qkvb/q_bf)
  unsigned short* q_bf  = (unsigned short*)(ws + 113246208);  // [2][32][1024][128] (dead after attn)
  unsigned short* k_bf  = (unsigned short*)(ws + 130023424);  // [2][8][1024][128]
  unsigned short* vt_bf = (unsigned short*)(ws + 134217728);  // [2][8][128][1024]
  unsigned short* a_bf  = (unsigned short*)(ws + 138412032);  // 2048x4096 bf16
  const long long PSTR = 2048LL * 2560;                       // partial stride (floats)

  cast_bf16<<<5120, 256, 0, stream>>>(x, x_bf, 2048 * 2560 / 4);
  tcast4<<<dim3(32, 80), 256, 0, stream>>>(wq, wqkvT, 4096, 2560, 0);
  tcast4<<<dim3(8, 80), 256, 0, stream>>>(wk, wqkvT, 1024, 2560, 4096);
  tcast4<<<dim3(8, 80), 256, 0, stream>>>(wv, wqkvT, 1024, 2560, 5120);
  tcast4<<<dim3(20, 128), 256, 0, stream>>>(wo, woT, 2560, 4096, 0);
  // QKV projection: 2048x6144x2560, bf16 output, single slice
  gemm256<<<dim3(192, 1), 512, 0, stream>>>(x_bf, wqkvT, nullptr, qkvb,
                                            6144, 2560, 2560, 2560, 24, 0);
  normrope<<<2048 * 48, 128, 0, stream>>>(qkvb, positions, qnw, knw, q_bf, k_bf, vt_bf);
  attn<<<dim3(8, 32, 2), 256, 0, stream>>>(q_bf, k_bf, vt_bf, a_bf);
  // out-projection: 2048x2560x4096, split-K=3 (1344/1344/1408), f32 partials
  gemm256<<<dim3(80, 3), 512, 0, stream>>>(a_bf, woT, p0, nullptr,
                                           2560, 4096, 1344, 4096, 10, PSTR);
  reduce3<<<5120, 256, 0, stream>>>((const float4*)p0, (const float4*)(p0 + PSTR),
                                    (const float4*)(p0 + 2 * PSTR), (float4*)out,
                                    2048 * 2560 / 4);
}

// Round 15
// 275.325 us; speedup vs baseline: 1.0687x; 1.0492x over previous
//
#include <hip/hip_runtime.h>
#include <hip/hip_bf16.h>

typedef __attribute__((ext_vector_type(8))) __bf16 bf8_t;
typedef __attribute__((ext_vector_type(4))) float f32x4;
typedef __attribute__((ext_vector_type(16))) float f32x16;

#define GLOAD16(gptr, lptr)                                                              \
  __builtin_amdgcn_global_load_lds((const __attribute__((address_space(1))) void*)(gptr), \
                                   (__attribute__((address_space(3))) void*)(lptr), 16, 0, 0)

__device__ __forceinline__ unsigned short f2bf(float f) {
  union { float f; unsigned u; } v; v.f = f;
  return (unsigned short)((v.u + 0x7fffu + ((v.u >> 16) & 1u)) >> 16);
}

__device__ __forceinline__ float bf2f(unsigned short u) {
  union { unsigned u; float f; } v; v.u = ((unsigned)u) << 16;
  return v.f;
}

__device__ __forceinline__ unsigned cvtpk_bf16(float a, float b) {
  unsigned r;
  asm("v_cvt_pk_bf16_f32 %0, %1, %2" : "=v"(r) : "v"(a), "v"(b));
  return r;
}

// ---------- cast f32 -> bf16 ----------
__global__ void cast_bf16(const float* __restrict__ in, unsigned short* __restrict__ out, int n4) {
  int i = blockIdx.x * blockDim.x + threadIdx.x;
  if (i >= n4) return;
  float4 v = ((const float4*)in)[i];
  ushort4 o;
  o.x = f2bf(v.x); o.y = f2bf(v.y); o.z = f2bf(v.z); o.w = f2bf(v.w);
  ((ushort4*)out)[i] = o;
}

// ---------- vectorized transpose-cast ----------
__global__ __launch_bounds__(256) void tcast4(const float* __restrict__ in,
                                              unsigned short* __restrict__ out,
                                              int C, int ld, int rowOff) {
  __shared__ float tile[128][40];
  int c0 = blockIdx.x * 128, r0 = blockIdx.y * 32;
  int tid = threadIdx.x;
  int tx = tid & 31, ty = tid >> 5;
  float4 v[4];
#pragma unroll
  for (int i = 0; i < 4; ++i)
    v[i] = *(const float4*)(in + (size_t)(r0 + (ty << 2) + i) * C + c0 + (tx << 2));
#pragma unroll
  for (int j = 0; j < 4; ++j) {
    float4 t4 = make_float4(v[0].x, v[1].x, v[2].x, v[3].x);
    if (j == 1) t4 = make_float4(v[0].y, v[1].y, v[2].y, v[3].y);
    if (j == 2) t4 = make_float4(v[0].z, v[1].z, v[2].z, v[3].z);
    if (j == 3) t4 = make_float4(v[0].w, v[1].w, v[2].w, v[3].w);
    *(float4*)(&tile[(tx << 2) + j][ty << 2]) = t4;
  }
  __syncthreads();
  int p = tid & 3;
#pragma unroll
  for (int half = 0; half < 2; ++half) {
    int cc = (tid >> 2) + half * 64;
    const float* row = &tile[cc][p << 3];
    unsigned u0 = ((unsigned)f2bf(row[1]) << 16) | f2bf(row[0]);
    unsigned u1 = ((unsigned)f2bf(row[3]) << 16) | f2bf(row[2]);
    unsigned u2 = ((unsigned)f2bf(row[5]) << 16) | f2bf(row[4]);
    unsigned u3 = ((unsigned)f2bf(row[7]) << 16) | f2bf(row[6]);
    *(uint4*)(out + (size_t)(rowOff + c0 + cc) * ld + r0 + (p << 3)) = make_uint4(u0, u1, u2, u3);
  }
}

// ---------- 256x256-tile bf16 GEMM, BK=32, 4-buffer 3-deep counted-vmcnt pipeline ----------
__global__ __launch_bounds__(512, 2) void gemm256(
    const unsigned short* __restrict__ A,
    const unsigned short* __restrict__ Bt,
    float* __restrict__ Cf, unsigned short* __restrict__ Cb,
    int N, int ldk, int Ks0, int Ktot, int nTileN, long long pstride) {
  __shared__ unsigned short SM[4][2][8192];
  int ks = blockIdx.y;
  int kbase = ks * Ks0;
  int Kslice = (ks == (int)gridDim.y - 1) ? (Ktot - kbase) : Ks0;
  int nwg = gridDim.x;
  int bidx = blockIdx.x;
  int wg = ((bidx & 7) * (nwg >> 3)) + (bidx >> 3);
  int bm = wg / nTileN, bn = wg % nTileN;
  int m0 = bm << 8, n0 = bn << 8;
  int tid = threadIdx.x, lane = tid & 63, w = tid >> 6;
  int wm = w >> 2, wn = w & 3;
  int lrow = lane & 15, lch = lane >> 4;
  int srow = tid >> 2;
  int scol = ((tid & 3) ^ ((srow >> 1) & 3)) << 3;
  int nt = Kslice >> 5;

  f32x4 acc[8][4] = {};

  auto stage = [&](int t) {
    int buf = t & 3;
    int k0 = kbase + (t << 5);
    const unsigned short* Ag = A + (size_t)(m0 + srow) * ldk + k0 + scol;
    const unsigned short* Bg = Bt + (size_t)(n0 + srow) * ldk + k0 + scol;
    unsigned short* Al = &SM[buf][0][w << 9];
    unsigned short* Bl = &SM[buf][1][w << 9];
    GLOAD16(Ag, Al);
    GLOAD16(Ag + (size_t)128 * ldk, Al + 4096);
    GLOAD16(Bg, Bl);
    GLOAD16(Bg + (size_t)128 * ldk, Bl + 4096);
  };

  stage(0);
  stage(1);
  stage(2);
  for (int t = 0; t < nt; ++t) {
    if (t + 2 < nt)      asm volatile("s_waitcnt vmcnt(8)" ::: "memory");
    else if (t + 1 < nt) asm volatile("s_waitcnt vmcnt(4)" ::: "memory");
    else                 asm volatile("s_waitcnt vmcnt(0)" ::: "memory");
    asm volatile("s_barrier" ::: "memory");
    if (t + 3 < nt) stage(t + 3);
    int buf = t & 3;
    const unsigned short* As = &SM[buf][0][0];
    const unsigned short* Bs = &SM[buf][1][0];
    bf8_t a[8], b[4];
#pragma unroll
    for (int mi = 0; mi < 8; ++mi) {
      int ar = (wm << 7) + (mi << 4) + lrow;
      a[mi] = *(const bf8_t*)(As + ar * 32 + ((lch ^ ((ar >> 1) & 3)) << 3));
    }
#pragma unroll
    for (int ni = 0; ni < 4; ++ni) {
      int br = (wn << 6) + (ni << 4) + lrow;
      b[ni] = *(const bf8_t*)(Bs + br * 32 + ((lch ^ ((br >> 1) & 3)) << 3));
    }
    __builtin_amdgcn_s_setprio(1);
#pragma unroll
    for (int mi = 0; mi < 8; ++mi)
#pragma unroll
      for (int ni = 0; ni < 4; ++ni)
        acc[mi][ni] = __builtin_amdgcn_mfma_f32_16x16x32_bf16(a[mi], b[ni], acc[mi][ni], 0, 0, 0);
    __builtin_amdgcn_s_setprio(0);
  }
  int r0 = m0 + (wm << 7) + (lch << 2);
  int c0 = n0 + (wn << 6) + lrow;
  if (Cb) {
#pragma unroll
    for (int mi = 0; mi < 8; ++mi)
#pragma unroll
      for (int ni = 0; ni < 4; ++ni)
#pragma unroll
        for (int r = 0; r < 4; ++r)
          Cb[(size_t)(r0 + (mi << 4) + r) * N + c0 + (ni << 4)] = f2bf(acc[mi][ni][r]);
  } else {
    float* __restrict__ C = Cf + (size_t)ks * pstride;
#pragma unroll
    for (int mi = 0; mi < 8; ++mi)
#pragma unroll
      for (int ni = 0; ni < 4; ++ni)
#pragma unroll
        for (int r = 0; r < 4; ++r)
          C[(size_t)(r0 + (mi << 4) + r) * N + c0 + (ni << 4)] = acc[mi][ni][r];
  }
}

// ---------- split-K 3-way reduce ----------
__global__ void reduce3(const float4* __restrict__ a, const float4* __restrict__ b,
                        const float4* __restrict__ c, float4* __restrict__ o, int n4) {
  int i = blockIdx.x * blockDim.x + threadIdx.x;
  if (i >= n4) return;
  float4 x = a[i], y = b[i], z = c[i];
  o[i] = make_float4(x.x + y.x + z.x, x.y + y.y + z.y, x.z + y.z + z.z, x.w + y.w + z.w);
}

// ---------- fused RMS-norm + RoPE + layout shuffle (bf16 input, K pre-scaled) ----------
__global__ __launch_bounds__(128) void normrope(
    const unsigned short* __restrict__ qkv, const int* __restrict__ positions,
    const float* __restrict__ qw, const float* __restrict__ kw,
    unsigned short* __restrict__ qb, unsigned short* __restrict__ kb,
    unsigned short* __restrict__ vt) {
  int blk = blockIdx.x;
  int hh = blk % 48, bt = blk / 48;
  int b = bt >> 10, t = bt & 1023;
  int tid = threadIdx.x;
  int colbase = (hh < 32) ? (hh << 7) : ((hh < 40) ? (4096 + ((hh - 32) << 7)) : (5120 + ((hh - 40) << 7)));
  float val = bf2f(qkv[(size_t)bt * 6144 + colbase + tid]);
  if (hh >= 40) {
    vt[((size_t)((b * 8 + hh - 40) * 128 + tid)) * 1024 + t] = f2bf(val);
    return;
  }
  __shared__ float red[2];
  __shared__ float xs[128];
  float ss = val * val;
#pragma unroll
  for (int m = 32; m >= 1; m >>= 1) ss += __shfl_xor(ss, m);
  if ((tid & 63) == 0) red[tid >> 6] = ss;
  __syncthreads();
  float rinv = rsqrtf((red[0] + red[1]) * (1.0f / 128.0f) + 1e-6f);
  float wgt = (hh < 32) ? qw[tid] : kw[tid];
  float xn = val * rinv * wgt;
  xs[tid] = xn;
  __syncthreads();
  float other = xs[tid ^ 64];
  int pos = positions[b * 1024 + t];
  int j = tid & 63;
  float ang = (float)pos * exp2f(-(float)j * 0.31143075889569027f);
  float sv = sinf(ang), cv = cosf(ang);
  float outv = (tid < 64) ? (xn * cv - other * sv) : (xn * cv + other * sv);
  if (hh >= 32) outv *= 0.12751744f;  // fold (1/sqrt(128))*log2(e) into K
  unsigned short o = f2bf(outv);
  if (hh < 32) qb[((size_t)((b * 32 + hh) * 1024 + t)) * 128 + tid] = o;
  else kb[((size_t)((b * 8 + hh - 32) * 1024 + t)) * 128 + tid] = o;
}

// ---------- flash attention (r11 best): K+V in LDS, in-reg softmax, defer-max, setprio ----------
__global__ __launch_bounds__(256, 2) void attn(
    const unsigned short* __restrict__ qb,
    const unsigned short* __restrict__ kb,
    const unsigned short* __restrict__ vt,
    unsigned short* __restrict__ ob) {
  __shared__ unsigned short Kl[2][64 * 128];   // 16B-slot swizzle: slot ^ (row&15)
  __shared__ unsigned short Vl[2][128 * 64];   // V^T tile; slot ^ (row&7)
  int bx = blockIdx.x, hq = blockIdx.y, b = blockIdx.z;
  int qt = (bx < 4) ? (7 - bx) : (bx - 4);     // longest-first dispatch (LPT)
  int kvh = hq >> 2;
  int tid = threadIdx.x, lane = tid & 63, w = tid >> 6;
  int qlane = lane & 31, h = lane >> 5;
  int q0 = (qt << 7) + (w << 5);
  int qg = q0 + qlane;
  const unsigned short* kbase = kb + ((size_t)(b * 8 + kvh) << 17);
  const unsigned short* vbase = vt + ((size_t)(b * 8 + kvh) << 17);

  const unsigned short* qptr = qb + ((size_t)((b * 32 + hq) * 1024 + qg) << 7) + (h << 3);
  bf8_t qf[8];
#pragma unroll
  for (int ds = 0; ds < 8; ++ds) qf[ds] = *(const bf8_t*)(qptr + ds * 16);

  f32x16 o[4] = {};
  float mrun = -3.0e38f, lrun = 0.f;
  int last_st = (q0 + 31) >> 6;
  int nsteps = 2 * qt + 2;

  auto stage = [&](int st, int buf) {
    int s0 = st << 6;
    unsigned short* kd = &Kl[buf][0];
    unsigned short* vd = &Vl[buf][0];
#pragma unroll
    for (int i = 0; i < 4; ++i) {
      int cid = i * 256 + tid;
      int kr = cid >> 4, ksl = cid & 15;
      GLOAD16(kbase + (size_t)(s0 + kr) * 128 + ((ksl ^ (kr & 15)) << 3), kd + cid * 8);
      int vr = cid >> 3, vsl = cid & 7;
      GLOAD16(vbase + (size_t)vr * 1024 + s0 + ((vsl ^ (vr & 7)) << 3), vd + cid * 8);
    }
  };

  stage(0, 0);
  for (int st = 0; st < nsteps; ++st) {
    __syncthreads();
    if (st + 1 < nsteps) stage(st + 1, (st + 1) & 1);
    if (st <= last_st) {
      const char* Kb = (const char*)&Kl[st & 1][0];
      const char* Vb = (const char*)&Vl[st & 1][0];
      f32x16 s0v = {}, s1v = {};
      __builtin_amdgcn_s_setprio(1);
#pragma unroll
      for (int ds = 0; ds < 8; ++ds) {
        int c = ds * 2 + h;
        int r0 = qlane, r1 = 32 + qlane;
        bf8_t k0 = *(const bf8_t*)(Kb + r0 * 256 + ((c ^ (r0 & 15)) << 4));
        bf8_t k1 = *(const bf8_t*)(Kb + r1 * 256 + ((c ^ (r1 & 15)) << 4));
        s0v = __builtin_amdgcn_mfma_f32_32x32x16_bf16(k0, qf[ds], s0v, 0, 0, 0);
        s1v = __builtin_amdgcn_mfma_f32_32x32x16_bf16(k1, qf[ds], s1v, 0, 0, 0);
      }
      __builtin_amdgcn_s_setprio(0);
      bool dm = (st == last_st);
      int kg0 = st << 6;
      float mt = -3.0e38f;
#pragma unroll
      for (int e = 0; e < 16; ++e) {
        int kl = (e & 3) + 8 * (e >> 2) + 4 * h;
        if (dm) {
          if (kg0 + kl > qg) s0v[e] = -3.0e38f;
          if (kg0 + 32 + kl > qg) s1v[e] = -3.0e38f;
        }
        mt = fmaxf(mt, fmaxf(s0v[e], s1v[e]));
      }
      mt = fmaxf(mt, __shfl_xor(mt, 32));
      if (!__all(mt - mrun <= 8.0f)) {
        float mnew = fmaxf(mrun, mt);
        float alpha = exp2f(mrun - mnew);
        lrun *= alpha;
#pragma unroll
        for (int db = 0; db < 4; ++db)
#pragma unroll
          for (int e = 0; e < 16; ++e) o[db][e] *= alpha;
        mrun = mnew;
      }
      float ls = 0.f;
#pragma unroll
      for (int e = 0; e < 16; ++e) {
        s0v[e] = exp2f(s0v[e] - mrun);
        s1v[e] = exp2f(s1v[e] - mrun);
        ls += s0v[e] + s1v[e];
      }
      ls += __shfl_xor(ls, 32);
      lrun += ls;
      bf8_t pf[4];
#pragma unroll
      for (int s = 0; s < 4; ++s) {
        unsigned w00, w01, w10, w11;
        {
          const int B0 = 4 * ((2 * s) & 3);
          if ((2 * s) >> 2) { w00 = cvtpk_bf16(s1v[B0], s1v[B0 + 1]); w01 = cvtpk_bf16(s1v[B0 + 2], s1v[B0 + 3]); }
          else              { w00 = cvtpk_bf16(s0v[B0], s0v[B0 + 1]); w01 = cvtpk_bf16(s0v[B0 + 2], s0v[B0 + 3]); }
        }
        {
          const int B1 = 4 * ((2 * s + 1) & 3);
          if ((2 * s + 1) >> 2) { w10 = cvtpk_bf16(s1v[B1], s1v[B1 + 1]); w11 = cvtpk_bf16(s1v[B1 + 2], s1v[B1 + 3]); }
          else                  { w10 = cvtpk_bf16(s0v[B1], s0v[B1 + 1]); w11 = cvtpk_bf16(s0v[B1 + 2], s0v[B1 + 3]); }
        }
        unsigned sa = h ? w00 : w10, sb = h ? w01 : w11;
        unsigned ra = __shfl_xor(sa, 32), rb = __shfl_xor(sb, 32);
        unsigned ka = h ? w10 : w00, kb2 = h ? w11 : w01;
        unsigned f0 = h ? ra : ka, f1 = h ? rb : kb2;
        unsigned f2 = h ? ka : ra, f3 = h ? kb2 : rb;
        uint4 fv = make_uint4(f0, f1, f2, f3);
        pf[s] = *(bf8_t*)&fv;
      }
      __builtin_amdgcn_s_setprio(1);
#pragma unroll
      for (int db = 0; db < 4; ++db) {
        int vr = (db << 5) + qlane;
#pragma unroll
        for (int s = 0; s < 4; ++s) {
          int c = (s << 1) + h;
          bf8_t vf = *(const bf8_t*)(Vb + vr * 128 + ((c ^ (vr & 7)) << 4));
          o[db] = __builtin_amdgcn_mfma_f32_32x32x16_bf16(vf, pf[s], o[db], 0, 0, 0);
        }
      }
      __builtin_amdgcn_s_setprio(0);
    }
  }

  __syncthreads();
  unsigned short* tb = &Kl[0][0] + (w << 12);
  float inv = 1.0f / lrun;
#pragma unroll
  for (int db = 0; db < 4; ++db)
#pragma unroll
    for (int rq = 0; rq < 4; ++rq) {
      int d0 = (db << 5) + (rq << 3) + (h << 2);
      unsigned lo = ((unsigned)f2bf(o[db][rq * 4 + 1] * inv) << 16) | f2bf(o[db][rq * 4 + 0] * inv);
      unsigned hi = ((unsigned)f2bf(o[db][rq * 4 + 3] * inv) << 16) | f2bf(o[db][rq * 4 + 2] * inv);
      *(uint2*)(tb + qlane * 128 + (d0 ^ ((qlane & 15) << 3))) = make_uint2(lo, hi);
    }
  int rr = lane >> 1, dh = (lane & 1) << 6;
  size_t orow = ((size_t)(b * 1024 + q0 + rr) << 12) + (hq << 7);
#pragma unroll
  for (int i = 0; i < 8; ++i) {
    int d8 = dh + i * 8;
    uint4 vv = *(const uint4*)(tb + rr * 128 + (d8 ^ ((rr & 15) << 3)));
    *(uint4*)(&ob[orow + d8]) = vv;
  }
}

extern "C" void kernel_launch(void* const* d_in, const int* in_sizes, int n_in,
                              void* d_out, int out_size, void* d_ws, size_t ws_size,
                              hipStream_t stream) {
  const float* x = (const float*)d_in[0];
  const int* positions = (const int*)d_in[1];
  const float* wq = (const float*)d_in[3];
  const float* wk = (const float*)d_in[4];
  const float* wv = (const float*)d_in[5];
  const float* wo = (const float*)d_in[6];
  const float* qnw = (const float*)d_in[7];
  const float* knw = (const float*)d_in[8];
  float* out = (float*)d_out;

  char* ws = (char*)d_ws;
  unsigned short* x_bf  = (unsigned short*)(ws);              // 2048x2560 bf16
  unsigned short* wqkvT = (unsigned short*)(ws + 10485760);   // 6144x2560 bf16
  unsigned short* woT   = (unsigned short*)(ws + 41943040);   // 2560x4096 bf16
  unsigned short* qkvb  = (unsigned short*)(ws + 62914560);   // 2048x6144 bf16 (dead after normrope)
  float*          p0    = (float*)(ws + 62914560);            // split-K partials x3 (reuse qkvb/q_bf)
  unsigned short* q_bf  = (unsigned short*)(ws + 113246208);  // [2][32][1024][128] (dead after attn)
  unsigned short* k_bf  = (unsigned short*)(ws + 130023424);  // [2][8][1024][128]
  unsigned short* vt_bf = (unsigned short*)(ws + 134217728);  // [2][8][128][1024]
  unsigned short* a_bf  = (unsigned short*)(ws + 138412032);  // 2048x4096 bf16
  const long long PSTR = 2048LL * 2560;                       // partial stride (floats)

  cast_bf16<<<5120, 256, 0, stream>>>(x, x_bf, 2048 * 2560 / 4);
  tcast4<<<dim3(32, 80), 256, 0, stream>>>(wq, wqkvT, 4096, 2560, 0);
  tcast4<<<dim3(8, 80), 256, 0, stream>>>(wk, wqkvT, 1024, 2560, 4096);
  tcast4<<<dim3(8, 80), 256, 0, stream>>>(wv, wqkvT, 1024, 2560, 5120);
  tcast4<<<dim3(20, 128), 256, 0, stream>>>(wo, woT, 2560, 4096, 0);
  // QKV projection: 2048x6144x2560, bf16 output, single slice
  gemm256<<<dim3(192, 1), 512, 0, stream>>>(x_bf, wqkvT, nullptr, qkvb,
                                            6144, 2560, 2560, 2560, 24, 0);
  normrope<<<2048 * 48, 128, 0, stream>>>(qkvb, positions, qnw, knw, q_bf, k_bf, vt_bf);
  attn<<<dim3(8, 32, 2), 256, 0, stream>>>(q_bf, k_bf, vt_bf, a_bf);
  // out-projection: 2048x2560x4096, split-K=3 (1344/1344/1408), f32 partials
  gemm256<<<dim3(80, 3), 512, 0, stream>>>(a_bf, woT, p0, nullptr,
                                           2560, 4096, 1344, 4096, 10, PSTR);
  reduce3<<<5120, 256, 0, stream>>>((const float4*)p0, (const float4*)(p0 + PSTR),
                                    (const float4*)(p0 + 2 * PSTR), (float4*)out,
                                    2048 * 2560 / 4);
}

// Round 16
// 272.873 us; speedup vs baseline: 1.0783x; 1.0090x over previous
//
#include <hip/hip_runtime.h>
#include <hip/hip_bf16.h>

typedef __attribute__((ext_vector_type(8))) __bf16 bf8_t;
typedef __attribute__((ext_vector_type(4))) float f32x4;
typedef __attribute__((ext_vector_type(16))) float f32x16;

#define GLOAD16(gptr, lptr)                                                              \
  __builtin_amdgcn_global_load_lds((const __attribute__((address_space(1))) void*)(gptr), \
                                   (__attribute__((address_space(3))) void*)(lptr), 16, 0, 0)

__device__ __forceinline__ unsigned short f2bf(float f) {
  union { float f; unsigned u; } v; v.f = f;
  return (unsigned short)((v.u + 0x7fffu + ((v.u >> 16) & 1u)) >> 16);
}

__device__ __forceinline__ float bf2f(unsigned short u) {
  union { unsigned u; float f; } v; v.u = ((unsigned)u) << 16;
  return v.f;
}

__device__ __forceinline__ unsigned cvtpk_bf16(float a, float b) {
  unsigned r;
  asm("v_cvt_pk_bf16_f32 %0, %1, %2" : "=v"(r) : "v"(a), "v"(b));
  return r;
}

// ---------- cast f32 -> bf16 ----------
__global__ void cast_bf16(const float* __restrict__ in, unsigned short* __restrict__ out, int n4) {
  int i = blockIdx.x * blockDim.x + threadIdx.x;
  if (i >= n4) return;
  float4 v = ((const float4*)in)[i];
  ushort4 o;
  o.x = f2bf(v.x); o.y = f2bf(v.y); o.z = f2bf(v.z); o.w = f2bf(v.w);
  ((ushort4*)out)[i] = o;
}

// ---------- vectorized transpose-cast ----------
__global__ __launch_bounds__(256) void tcast4(const float* __restrict__ in,
                                              unsigned short* __restrict__ out,
                                              int C, int ld, int rowOff) {
  __shared__ float tile[128][40];
  int c0 = blockIdx.x * 128, r0 = blockIdx.y * 32;
  int tid = threadIdx.x;
  int tx = tid & 31, ty = tid >> 5;
  float4 v[4];
#pragma unroll
  for (int i = 0; i < 4; ++i)
    v[i] = *(const float4*)(in + (size_t)(r0 + (ty << 2) + i) * C + c0 + (tx << 2));
#pragma unroll
  for (int j = 0; j < 4; ++j) {
    float4 t4 = make_float4(v[0].x, v[1].x, v[2].x, v[3].x);
    if (j == 1) t4 = make_float4(v[0].y, v[1].y, v[2].y, v[3].y);
    if (j == 2) t4 = make_float4(v[0].z, v[1].z, v[2].z, v[3].z);
    if (j == 3) t4 = make_float4(v[0].w, v[1].w, v[2].w, v[3].w);
    *(float4*)(&tile[(tx << 2) + j][ty << 2]) = t4;
  }
  __syncthreads();
  int p = tid & 3;
#pragma unroll
  for (int half = 0; half < 2; ++half) {
    int cc = (tid >> 2) + half * 64;
    const float* row = &tile[cc][p << 3];
    unsigned u0 = ((unsigned)f2bf(row[1]) << 16) | f2bf(row[0]);
    unsigned u1 = ((unsigned)f2bf(row[3]) << 16) | f2bf(row[2]);
    unsigned u2 = ((unsigned)f2bf(row[5]) << 16) | f2bf(row[4]);
    unsigned u3 = ((unsigned)f2bf(row[7]) << 16) | f2bf(row[6]);
    *(uint4*)(out + (size_t)(rowOff + c0 + cc) * ld + r0 + (p << 3)) = make_uint4(u0, u1, u2, u3);
  }
}

// ---------- 256x256-tile bf16 GEMM, BK=32, 4-buffer 3-deep counted-vmcnt pipeline ----------
// swz2d=1: 2D XCD chunking (8 XCDs x [bm 0..7 x 3 bn]) -> per-XCD B working set 3.75MB <= L2.
__global__ __launch_bounds__(512, 2) void gemm256(
    const unsigned short* __restrict__ A,
    const unsigned short* __restrict__ Bt,
    float* __restrict__ Cf, unsigned short* __restrict__ Cb,
    int N, int ldk, int Ks0, int Ktot, int nTileN, long long pstride, int swz2d) {
  __shared__ unsigned short SM[4][2][8192];
  int ks = blockIdx.y;
  int kbase = ks * Ks0;
  int Kslice = (ks == (int)gridDim.y - 1) ? (Ktot - kbase) : Ks0;
  int nwg = gridDim.x;
  int bidx = blockIdx.x;
  int bm, bn;
  if (swz2d) {  // QKV: 192 blocks = 8 XCD x (8 bm x 3 bn)
    int i = bidx >> 3;
    bm = i / 3;
    bn = (bidx & 7) * 3 + i % 3;
  } else {
    int wg = ((bidx & 7) * (nwg >> 3)) + (bidx >> 3);
    bm = wg / nTileN;
    bn = wg % nTileN;
  }
  int m0 = bm << 8, n0 = bn << 8;
  int tid = threadIdx.x, lane = tid & 63, w = tid >> 6;
  int wm = w >> 2, wn = w & 3;
  int lrow = lane & 15, lch = lane >> 4;
  int srow = tid >> 2;
  int scol = ((tid & 3) ^ ((srow >> 1) & 3)) << 3;
  int nt = Kslice >> 5;

  f32x4 acc[8][4] = {};

  auto stage = [&](int t) {
    int buf = t & 3;
    int k0 = kbase + (t << 5);
    const unsigned short* Ag = A + (size_t)(m0 + srow) * ldk + k0 + scol;
    const unsigned short* Bg = Bt + (size_t)(n0 + srow) * ldk + k0 + scol;
    unsigned short* Al = &SM[buf][0][w << 9];
    unsigned short* Bl = &SM[buf][1][w << 9];
    GLOAD16(Ag, Al);
    GLOAD16(Ag + (size_t)128 * ldk, Al + 4096);
    GLOAD16(Bg, Bl);
    GLOAD16(Bg + (size_t)128 * ldk, Bl + 4096);
  };

  stage(0);
  stage(1);
  stage(2);
  for (int t = 0; t < nt; ++t) {
    if (t + 2 < nt)      asm volatile("s_waitcnt vmcnt(8)" ::: "memory");
    else if (t + 1 < nt) asm volatile("s_waitcnt vmcnt(4)" ::: "memory");
    else                 asm volatile("s_waitcnt vmcnt(0)" ::: "memory");
    asm volatile("s_barrier" ::: "memory");
    if (t + 3 < nt) stage(t + 3);
    int buf = t & 3;
    const unsigned short* As = &SM[buf][0][0];
    const unsigned short* Bs = &SM[buf][1][0];
    bf8_t a[8], b[4];
#pragma unroll
    for (int mi = 0; mi < 8; ++mi) {
      int ar = (wm << 7) + (mi << 4) + lrow;
      a[mi] = *(const bf8_t*)(As + ar * 32 + ((lch ^ ((ar >> 1) & 3)) << 3));
    }
#pragma unroll
    for (int ni = 0; ni < 4; ++ni) {
      int br = (wn << 6) + (ni << 4) + lrow;
      b[ni] = *(const bf8_t*)(Bs + br * 32 + ((lch ^ ((br >> 1) & 3)) << 3));
    }
    __builtin_amdgcn_s_setprio(1);
#pragma unroll
    for (int mi = 0; mi < 8; ++mi)
#pragma unroll
      for (int ni = 0; ni < 4; ++ni)
        acc[mi][ni] = __builtin_amdgcn_mfma_f32_16x16x32_bf16(a[mi], b[ni], acc[mi][ni], 0, 0, 0);
    __builtin_amdgcn_s_setprio(0);
  }
  int r0 = m0 + (wm << 7) + (lch << 2);
  int c0 = n0 + (wn << 6) + lrow;
  if (Cb) {
#pragma unroll
    for (int mi = 0; mi < 8; ++mi)
#pragma unroll
      for (int ni = 0; ni < 4; ++ni)
#pragma unroll
        for (int r = 0; r < 4; ++r)
          Cb[(size_t)(r0 + (mi << 4) + r) * N + c0 + (ni << 4)] = f2bf(acc[mi][ni][r]);
  } else {
    float* __restrict__ C = Cf + (size_t)ks * pstride;
#pragma unroll
    for (int mi = 0; mi < 8; ++mi)
#pragma unroll
      for (int ni = 0; ni < 4; ++ni)
#pragma unroll
        for (int r = 0; r < 4; ++r)
          C[(size_t)(r0 + (mi << 4) + r) * N + c0 + (ni << 4)] = acc[mi][ni][r];
  }
}

// ---------- split-K 3-way reduce ----------
__global__ void reduce3(const float4* __restrict__ a, const float4* __restrict__ b,
                        const float4* __restrict__ c, float4* __restrict__ o, int n4) {
  int i = blockIdx.x * blockDim.x + threadIdx.x;
  if (i >= n4) return;
  float4 x = a[i], y = b[i], z = c[i];
  o[i] = make_float4(x.x + y.x + z.x, x.y + y.y + z.y, x.z + y.z + z.z, x.w + y.w + z.w);
}

// ---------- fused RMS-norm + RoPE + layout shuffle (bf16 input, K pre-scaled) ----------
__global__ __launch_bounds__(128) void normrope(
    const unsigned short* __restrict__ qkv, const int* __restrict__ positions,
    const float* __restrict__ qw, const float* __restrict__ kw,
    unsigned short* __restrict__ qb, unsigned short* __restrict__ kb,
    unsigned short* __restrict__ vt) {
  int blk = blockIdx.x;
  int hh = blk % 48, bt = blk / 48;
  int b = bt >> 10, t = bt & 1023;
  int tid = threadIdx.x;
  int colbase = (hh < 32) ? (hh << 7) : ((hh < 40) ? (4096 + ((hh - 32) << 7)) : (5120 + ((hh - 40) << 7)));
  float val = bf2f(qkv[(size_t)bt * 6144 + colbase + tid]);
  if (hh >= 40) {
    vt[((size_t)((b * 8 + hh - 40) * 128 + tid)) * 1024 + t] = f2bf(val);
    return;
  }
  __shared__ float red[2];
  __shared__ float xs[128];
  float ss = val * val;
#pragma unroll
  for (int m = 32; m >= 1; m >>= 1) ss += __shfl_xor(ss, m);
  if ((tid & 63) == 0) red[tid >> 6] = ss;
  __syncthreads();
  float rinv = rsqrtf((red[0] + red[1]) * (1.0f / 128.0f) + 1e-6f);
  float wgt = (hh < 32) ? qw[tid] : kw[tid];
  float xn = val * rinv * wgt;
  xs[tid] = xn;
  __syncthreads();
  float other = xs[tid ^ 64];
  int pos = positions[b * 1024 + t];
  int j = tid & 63;
  float ang = (float)pos * exp2f(-(float)j * 0.31143075889569027f);
  float sv = sinf(ang), cv = cosf(ang);
  float outv = (tid < 64) ? (xn * cv - other * sv) : (xn * cv + other * sv);
  if (hh >= 32) outv *= 0.12751744f;  // fold (1/sqrt(128))*log2(e) into K
  unsigned short o = f2bf(outv);
  if (hh < 32) qb[((size_t)((b * 32 + hh) * 1024 + t)) * 128 + tid] = o;
  else kb[((size_t)((b * 8 + hh - 32) * 1024 + t)) * 128 + tid] = o;
}

// ---------- flash attention (r11 best): K+V in LDS, in-reg softmax, defer-max, setprio ----------
__global__ __launch_bounds__(256, 2) void attn(
    const unsigned short* __restrict__ qb,
    const unsigned short* __restrict__ kb,
    const unsigned short* __restrict__ vt,
    unsigned short* __restrict__ ob) {
  __shared__ unsigned short Kl[2][64 * 128];   // 16B-slot swizzle: slot ^ (row&15)
  __shared__ unsigned short Vl[2][128 * 64];   // V^T tile; slot ^ (row&7)
  int bx = blockIdx.x, hq = blockIdx.y, b = blockIdx.z;
  int qt = (bx < 4) ? (7 - bx) : (bx - 4);     // longest-first dispatch (LPT)
  int kvh = hq >> 2;
  int tid = threadIdx.x, lane = tid & 63, w = tid >> 6;
  int qlane = lane & 31, h = lane >> 5;
  int q0 = (qt << 7) + (w << 5);
  int qg = q0 + qlane;
  const unsigned short* kbase = kb + ((size_t)(b * 8 + kvh) << 17);
  const unsigned short* vbase = vt + ((size_t)(b * 8 + kvh) << 17);

  const unsigned short* qptr = qb + ((size_t)((b * 32 + hq) * 1024 + qg) << 7) + (h << 3);
  bf8_t qf[8];
#pragma unroll
  for (int ds = 0; ds < 8; ++ds) qf[ds] = *(const bf8_t*)(qptr + ds * 16);

  f32x16 o[4] = {};
  float mrun = -3.0e38f, lrun = 0.f;
  int last_st = (q0 + 31) >> 6;
  int nsteps = 2 * qt + 2;

  auto stage = [&](int st, int buf) {
    int s0 = st << 6;
    unsigned short* kd = &Kl[buf][0];
    unsigned short* vd = &Vl[buf][0];
#pragma unroll
    for (int i = 0; i < 4; ++i) {
      int cid = i * 256 + tid;
      int kr = cid >> 4, ksl = cid & 15;
      GLOAD16(kbase + (size_t)(s0 + kr) * 128 + ((ksl ^ (kr & 15)) << 3), kd + cid * 8);
      int vr = cid >> 3, vsl = cid & 7;
      GLOAD16(vbase + (size_t)vr * 1024 + s0 + ((vsl ^ (vr & 7)) << 3), vd + cid * 8);
    }
  };

  stage(0, 0);
  for (int st = 0; st < nsteps; ++st) {
    __syncthreads();
    if (st + 1 < nsteps) stage(st + 1, (st + 1) & 1);
    if (st <= last_st) {
      const char* Kb = (const char*)&Kl[st & 1][0];
      const char* Vb = (const char*)&Vl[st & 1][0];
      f32x16 s0v = {}, s1v = {};
      __builtin_amdgcn_s_setprio(1);
#pragma unroll
      for (int ds = 0; ds < 8; ++ds) {
        int c = ds * 2 + h;
        int r0 = qlane, r1 = 32 + qlane;
        bf8_t k0 = *(const bf8_t*)(Kb + r0 * 256 + ((c ^ (r0 & 15)) << 4));
        bf8_t k1 = *(const bf8_t*)(Kb + r1 * 256 + ((c ^ (r1 & 15)) << 4));
        s0v = __builtin_amdgcn_mfma_f32_32x32x16_bf16(k0, qf[ds], s0v, 0, 0, 0);
        s1v = __builtin_amdgcn_mfma_f32_32x32x16_bf16(k1, qf[ds], s1v, 0, 0, 0);
      }
      __builtin_amdgcn_s_setprio(0);
      bool dm = (st == last_st);
      int kg0 = st << 6;
      float mt = -3.0e38f;
#pragma unroll
      for (int e = 0; e < 16; ++e) {
        int kl = (e & 3) + 8 * (e >> 2) + 4 * h;
        if (dm) {
          if (kg0 + kl > qg) s0v[e] = -3.0e38f;
          if (kg0 + 32 + kl > qg) s1v[e] = -3.0e38f;
        }
        mt = fmaxf(mt, fmaxf(s0v[e], s1v[e]));
      }
      mt = fmaxf(mt, __shfl_xor(mt, 32));
      if (!__all(mt - mrun <= 8.0f)) {
        float mnew = fmaxf(mrun, mt);
        float alpha = exp2f(mrun - mnew);
        lrun *= alpha;
#pragma unroll
        for (int db = 0; db < 4; ++db)
#pragma unroll
          for (int e = 0; e < 16; ++e) o[db][e] *= alpha;
        mrun = mnew;
      }
      float ls = 0.f;
#pragma unroll
      for (int e = 0; e < 16; ++e) {
        s0v[e] = exp2f(s0v[e] - mrun);
        s1v[e] = exp2f(s1v[e] - mrun);
        ls += s0v[e] + s1v[e];
      }
      ls += __shfl_xor(ls, 32);
      lrun += ls;
      bf8_t pf[4];
#pragma unroll
      for (int s = 0; s < 4; ++s) {
        unsigned w00, w01, w10, w11;
        {
          const int B0 = 4 * ((2 * s) & 3);
          if ((2 * s) >> 2) { w00 = cvtpk_bf16(s1v[B0], s1v[B0 + 1]); w01 = cvtpk_bf16(s1v[B0 + 2], s1v[B0 + 3]); }
          else              { w00 = cvtpk_bf16(s0v[B0], s0v[B0 + 1]); w01 = cvtpk_bf16(s0v[B0 + 2], s0v[B0 + 3]); }
        }
        {
          const int B1 = 4 * ((2 * s + 1) & 3);
          if ((2 * s + 1) >> 2) { w10 = cvtpk_bf16(s1v[B1], s1v[B1 + 1]); w11 = cvtpk_bf16(s1v[B1 + 2], s1v[B1 + 3]); }
          else                  { w10 = cvtpk_bf16(s0v[B1], s0v[B1 + 1]); w11 = cvtpk_bf16(s0v[B1 + 2], s0v[B1 + 3]); }
        }
        unsigned sa = h ? w00 : w10, sb = h ? w01 : w11;
        unsigned ra = __shfl_xor(sa, 32), rb = __shfl_xor(sb, 32);
        unsigned ka = h ? w10 : w00, kb2 = h ? w11 : w01;
        unsigned f0 = h ? ra : ka, f1 = h ? rb : kb2;
        unsigned f2 = h ? ka : ra, f3 = h ? kb2 : rb;
        uint4 fv = make_uint4(f0, f1, f2, f3);
        pf[s] = *(bf8_t*)&fv;
      }
      __builtin_amdgcn_s_setprio(1);
#pragma unroll
      for (int db = 0; db < 4; ++db) {
        int vr = (db << 5) + qlane;
#pragma unroll
        for (int s = 0; s < 4; ++s) {
          int c = (s << 1) + h;
          bf8_t vf = *(const bf8_t*)(Vb + vr * 128 + ((c ^ (vr & 7)) << 4));
          o[db] = __builtin_amdgcn_mfma_f32_32x32x16_bf16(vf, pf[s], o[db], 0, 0, 0);
        }
      }
      __builtin_amdgcn_s_setprio(0);
    }
  }

  __syncthreads();
  unsigned short* tb = &Kl[0][0] + (w << 12);
  float inv = 1.0f / lrun;
#pragma unroll
  for (int db = 0; db < 4; ++db)
#pragma unroll
    for (int rq = 0; rq < 4; ++rq) {
      int d0 = (db << 5) + (rq << 3) + (h << 2);
      unsigned lo = ((unsigned)f2bf(o[db][rq * 4 + 1] * inv) << 16) | f2bf(o[db][rq * 4 + 0] * inv);
      unsigned hi = ((unsigned)f2bf(o[db][rq * 4 + 3] * inv) << 16) | f2bf(o[db][rq * 4 + 2] * inv);
      *(uint2*)(tb + qlane * 128 + (d0 ^ ((qlane & 15) << 3))) = make_uint2(lo, hi);
    }
  int rr = lane >> 1, dh = (lane & 1) << 6;
  size_t orow = ((size_t)(b * 1024 + q0 + rr) << 12) + (hq << 7);
#pragma unroll
  for (int i = 0; i < 8; ++i) {
    int d8 = dh + i * 8;
    uint4 vv = *(const uint4*)(tb + rr * 128 + (d8 ^ ((rr & 15) << 3)));
    *(uint4*)(&ob[orow + d8]) = vv;
  }
}

extern "C" void kernel_launch(void* const* d_in, const int* in_sizes, int n_in,
                              void* d_out, int out_size, void* d_ws, size_t ws_size,
                              hipStream_t stream) {
  const float* x = (const float*)d_in[0];
  const int* positions = (const int*)d_in[1];
  const float* wq = (const float*)d_in[3];
  const float* wk = (const float*)d_in[4];
  const float* wv = (const float*)d_in[5];
  const float* wo = (const float*)d_in[6];
  const float* qnw = (const float*)d_in[7];
  const float* knw = (const float*)d_in[8];
  float* out = (float*)d_out;

  char* ws = (char*)d_ws;
  unsigned short* x_bf  = (unsigned short*)(ws);              // 2048x2560 bf16
  unsigned short* wqkvT = (unsigned short*)(ws + 10485760);   // 6144x2560 bf16
  unsigned short* woT   = (unsigned short*)(ws + 41943040);   // 2560x4096 bf16
  unsigned short* qkvb  = (unsigned short*)(ws + 62914560);   // 2048x6144 bf16 (dead after normrope)
  float*          p0    = (float*)(ws + 62914560);            // split-K partials x3 (reuse qkvb/q_bf)
  unsigned short* q_bf  = (unsigned short*)(ws + 113246208);  // [2][32][1024][128] (dead after attn)
  unsigned short* k_bf  = (unsigned short*)(ws + 130023424);  // [2][8][1024][128]
  unsigned short* vt_bf = (unsigned short*)(ws + 134217728);  // [2][8][128][1024]
  unsigned short* a_bf  = (unsigned short*)(ws + 138412032);  // 2048x4096 bf16
  const long long PSTR = 2048LL * 2560;                       // partial stride (floats)

  cast_bf16<<<5120, 256, 0, stream>>>(x, x_bf, 2048 * 2560 / 4);
  tcast4<<<dim3(32, 80), 256, 0, stream>>>(wq, wqkvT, 4096, 2560, 0);
  tcast4<<<dim3(8, 80), 256, 0, stream>>>(wk, wqkvT, 1024, 2560, 4096);
  tcast4<<<dim3(8, 80), 256, 0, stream>>>(wv, wqkvT, 1024, 2560, 5120);
  tcast4<<<dim3(20, 128), 256, 0, stream>>>(wo, woT, 2560, 4096, 0);
  // QKV projection: 2048x6144x2560, bf16 output, 2D XCD chunking (swz2d=1)
  gemm256<<<dim3(192, 1), 512, 0, stream>>>(x_bf, wqkvT, nullptr, qkvb,
                                            6144, 2560, 2560, 2560, 24, 0, 1);
  normrope<<<2048 * 48, 128, 0, stream>>>(qkvb, positions, qnw, knw, q_bf, k_bf, vt_bf);
  attn<<<dim3(8, 32, 2), 256, 0, stream>>>(q_bf, k_bf, vt_bf, a_bf);
  // out-projection: 2048x2560x4096, split-K=3 (1344/1344/1408), f32 partials
  gemm256<<<dim3(80, 3), 512, 0, stream>>>(a_bf, woT, p0, nullptr,
                                           2560, 4096, 1344, 4096, 10, PSTR, 0);
  reduce3<<<5120, 256, 0, stream>>>((const float4*)p0, (const float4*)(p0 + PSTR),
                                    (const float4*)(p0 + 2 * PSTR), (float4*)out,
                                    2048 * 2560 / 4);
}